// Round 18
// baseline (252.976 us; speedup 1.0000x reference)
//
#include <hip/hip_runtime.h>
#include <stdint.h>

typedef __attribute__((ext_vector_type(8))) short bf16x8;
typedef __attribute__((ext_vector_type(4))) float f32x4;
typedef __attribute__((ext_vector_type(4))) unsigned int u32x4;

static constexpr int B_ = 4, T_ = 2048, D_ = 1024, H_ = 16, HD_ = 64;
static constexpr int BT_ = B_ * T_;
static constexpr float LOG2E_OVER_8 = 0.18033688011112042f;  // log2(e)/8

#define DEV static __device__ __forceinline__

// raw barrier with scheduling fences (no vmcnt drain, unlike __syncthreads)
#define RAW_BAR() do { \
    __builtin_amdgcn_sched_barrier(0); \
    __builtin_amdgcn_s_barrier(); \
    __builtin_amdgcn_sched_barrier(0); \
} while (0)

DEV unsigned short f2bf(float f) {
    union { float f; uint32_t u; } v; v.f = f;
    uint32_t u = v.u;
    uint32_t r = (u + 0x7fffu + ((u >> 16) & 1u)) >> 16;  // RN-even
    return (unsigned short)r;
}

DEV uint32_t cvt_pk_bf16(float lo, float hi) {
    uint32_t r;
    asm("v_cvt_pk_bf16_f32 %0, %1, %2" : "=v"(r) : "v"(lo), "v"(hi));
    return r;
}

DEV float fexp2(float x) {   // raw v_exp_f32 (2^x)
    float r;
    asm("v_exp_f32 %0, %1" : "=v"(r) : "v"(x));
    return r;
}

DEV void gll16(const void* g, void* l) {
    __builtin_amdgcn_global_load_lds(
        (const __attribute__((address_space(1))) void*)g,
        (__attribute__((address_space(3))) void*)l, 16, 0, 0);
}

// ---------------- cast fp32 -> bf16: weight matrices only ----------------
__global__ __launch_bounds__(256)
void cast_fused(const float* __restrict__ wq, const float* __restrict__ wk,
                const float* __restrict__ wv, const float* __restrict__ wo,
                unsigned short* __restrict__ owq, unsigned short* __restrict__ owk,
                unsigned short* __restrict__ owv, unsigned short* __restrict__ owo) {
    const int y = blockIdx.y;
    const float* s; unsigned short* d;
    switch (y) {
        case 0: s = wq; d = owq; break;
        case 1: s = wk; d = owk; break;
        case 2: s = wv; d = owv; break;
        default: s = wo; d = owo; break;
    }
    const int n4 = D_ * D_ / 4;
    for (int i = blockIdx.x * blockDim.x + threadIdx.x; i < n4; i += gridDim.x * blockDim.x) {
        float4 vv = reinterpret_cast<const float4*>(s)[i];
        ushort4 o;
        o.x = f2bf(vv.x); o.y = f2bf(vv.y); o.z = f2bf(vv.z); o.w = f2bf(vv.w);
        reinterpret_cast<ushort4*>(d)[i] = o;
    }
}

// ---------------- fused QKV projection GEMM: fp32 A reg-staged (cast fused in) ----------------
// z==0: q out (scaled log2e/8), z==1: k out, z==2: V out written DIRECTLY to vT
__global__ __launch_bounds__(256, 3)
void gemm_qkv(const float* __restrict__ Aq, const float* __restrict__ Ak,
              const float* __restrict__ Av,
              const unsigned short* __restrict__ Wqb, const unsigned short* __restrict__ Wkb,
              const unsigned short* __restrict__ Wvb,
              const float* __restrict__ bq, const float* __restrict__ bk,
              const float* __restrict__ bv,
              unsigned short* __restrict__ oq, unsigned short* __restrict__ ok,
              unsigned short* __restrict__ vT) {
    constexpr int K = 1024, N = 1024, BK = 64;
    __shared__ unsigned short sA[128 * BK];   // 16KB
    __shared__ unsigned short sB[128 * BK];   // 16KB
    // XCD swizzle: 1536 blocks -> 192 contiguous (z,bm,bn) per XCD; A-panels XCD-local
    const int flat = blockIdx.x + (blockIdx.y << 3) + (blockIdx.z << 9);
    const int nbz = (flat & 7) * 192 + (flat >> 3);
    const int z = nbz >> 9;
    const int rem = nbz & 511;
    const int bm = rem >> 3, bn = rem & 7;

    const float* A = z == 0 ? Aq : z == 1 ? Ak : Av;
    const unsigned short* W = z == 0 ? Wqb : z == 1 ? Wkb : Wvb;
    const float* bias        = z == 0 ? bq : z == 1 ? bk : bv;
    const float oscale       = z == 0 ? LOG2E_OVER_8 : 1.0f;

    const int tid = threadIdx.x;
    const int lane = tid & 63, w = tid >> 6;
    const int c = lane & 15, g = lane >> 4;
    const int wr = w >> 1, wc = w & 1;
    const int rowA0 = bm * 128, rowB0 = bn * 128;

    f32x4 acc[4][4] = {};

    for (int k0 = 0; k0 < K; k0 += BK) {
        __syncthreads();
        // W: async global->LDS (bf16, pre-cast)
#pragma unroll
        for (int i = 0; i < 4; ++i) {
            int chunk = tid + i * 256;          // 0..1023
            int row = chunk >> 3, c16 = chunk & 7;
            int sc16 = c16 ^ (row & 7);          // source-side swizzle
            gll16(W + (size_t)(rowB0 + row) * K + k0 + sc16 * 8, (char*)sB + chunk * 16);
        }
        // A: reg-staged fp32 -> bf16 (cast fused; same LDS image as before)
#pragma unroll
        for (int i = 0; i < 4; ++i) {
            int chunk = tid + i * 256;
            int row = chunk >> 3, c16 = chunk & 7;
            int sc16 = c16 ^ (row & 7);
            const float* src = A + (size_t)(rowA0 + row) * K + k0 + sc16 * 8;
            float4 lo = *reinterpret_cast<const float4*>(src);
            float4 hi = *reinterpret_cast<const float4*>(src + 4);
            u32x4 pk;
            pk.x = cvt_pk_bf16(lo.x, lo.y);
            pk.y = cvt_pk_bf16(lo.z, lo.w);
            pk.z = cvt_pk_bf16(hi.x, hi.y);
            pk.w = cvt_pk_bf16(hi.z, hi.w);
            *reinterpret_cast<u32x4*>((char*)sA + chunk * 16) = pk;
        }
        __syncthreads();
#pragma unroll
        for (int kk = 0; kk < 2; ++kk) {
            bf16x8 af[4], bfr[4];
#pragma unroll
            for (int mf = 0; mf < 4; ++mf) {
                int row = wr * 64 + mf * 16 + c;
                int off = (row * 128 + kk * 64 + g * 16) ^ ((row & 7) << 4);
                af[mf] = *reinterpret_cast<const bf16x8*>((const char*)sA + off);
            }
#pragma unroll
            for (int nf = 0; nf < 4; ++nf) {
                int row = wc * 64 + nf * 16 + c;
                int off = (row * 128 + kk * 64 + g * 16) ^ ((row & 7) << 4);
                bfr[nf] = *reinterpret_cast<const bf16x8*>((const char*)sB + off);
            }
#pragma unroll
            for (int mf = 0; mf < 4; ++mf)
#pragma unroll
                for (int nf = 0; nf < 4; ++nf)
                    acc[mf][nf] = __builtin_amdgcn_mfma_f32_16x16x32_bf16(af[mf], bfr[nf], acc[mf][nf], 0, 0, 0);
        }
    }

    if (z == 2) {
        // direct transposed+permuted write into vT[b][h][d][t]
#pragma unroll
        for (int mf = 0; mf < 4; ++mf) {
            int rowbase = rowA0 + wr * 64 + mf * 16 + g * 4;   // multiple of 4
            int bb = rowbase >> 11;
            int trow = rowbase & 2047;
            int blk = trow >> 6, off = trow & 63;              // off multiple of 4
            int slot = (off & 32) | ((off & 8) << 1) | ((off & 4) << 1) | ((off & 16) >> 2);
#pragma unroll
            for (int nf = 0; nf < 4; ++nf) {
                int col = rowB0 + wc * 64 + nf * 16 + c;       // = h*64 + d
                float bvv = bias[col];
                int hh = col >> 6, d = col & 63;
                ushort4 o;
                o.x = f2bf(acc[mf][nf][0] + bvv);
                o.y = f2bf(acc[mf][nf][1] + bvv);
                o.z = f2bf(acc[mf][nf][2] + bvv);
                o.w = f2bf(acc[mf][nf][3] + bvv);
                size_t addr = (((size_t)(bb * H_ + hh)) * HD_ + d) * T_ + blk * 64 + slot;
                *reinterpret_cast<ushort4*>(&vT[addr]) = o;
            }
        }
    } else {
        unsigned short* out = z == 0 ? oq : ok;
#pragma unroll
        for (int mf = 0; mf < 4; ++mf)
#pragma unroll
            for (int nf = 0; nf < 4; ++nf) {
                int col = rowB0 + wc * 64 + nf * 16 + c;
                float bvv = bias[col];
#pragma unroll
                for (int j = 0; j < 4; ++j) {
                    int row = rowA0 + wr * 64 + mf * 16 + g * 4 + j;
                    float v = (acc[mf][nf][j] + bvv) * oscale;
                    out[(size_t)row * N + col] = f2bf(v);
                }
            }
    }
}

// ---------------- O projection GEMM (fp32 out, single-buffer, XCD swizzle) ----------------
__global__ __launch_bounds__(256, 3)
void gemm_o(const unsigned short* __restrict__ A, const unsigned short* __restrict__ W,
            const float* __restrict__ bias, float* __restrict__ out) {
    constexpr int K = 1024, N = 1024, BK = 64;
    __shared__ unsigned short sA[128 * BK];
    __shared__ unsigned short sB[128 * BK];
    const int tid = threadIdx.x;
    const int lane = tid & 63, w = tid >> 6;
    const int c = lane & 15, g = lane >> 4;
    // XCD swizzle: 512 blocks -> 64 contiguous (bm,bn) per XCD
    const int flat = blockIdx.x + (blockIdx.y << 3);
    const int nbz = (flat & 7) * 64 + (flat >> 3);
    const int bm = nbz >> 3, bn = nbz & 7;
    const int wr = w >> 1, wc = w & 1;
    const int rowA0 = bm * 128, rowB0 = bn * 128;

    f32x4 acc[4][4] = {};

    for (int k0 = 0; k0 < K; k0 += BK) {
        __syncthreads();
#pragma unroll
        for (int i = 0; i < 4; ++i) {
            int chunk = tid + i * 256;
            int row = chunk >> 3, c16 = chunk & 7;
            int sc16 = c16 ^ (row & 7);
            gll16(A + (size_t)(rowA0 + row) * K + k0 + sc16 * 8, (char*)sA + chunk * 16);
            gll16(W + (size_t)(rowB0 + row) * K + k0 + sc16 * 8, (char*)sB + chunk * 16);
        }
        __syncthreads();
#pragma unroll
        for (int kk = 0; kk < 2; ++kk) {
            bf16x8 af[4], bfr[4];
#pragma unroll
            for (int mf = 0; mf < 4; ++mf) {
                int row = wr * 64 + mf * 16 + c;
                int off = (row * 128 + kk * 64 + g * 16) ^ ((row & 7) << 4);
                af[mf] = *reinterpret_cast<const bf16x8*>((const char*)sA + off);
            }
#pragma unroll
            for (int nf = 0; nf < 4; ++nf) {
                int row = wc * 64 + nf * 16 + c;
                int off = (row * 128 + kk * 64 + g * 16) ^ ((row & 7) << 4);
                bfr[nf] = *reinterpret_cast<const bf16x8*>((const char*)sB + off);
            }
#pragma unroll
            for (int mf = 0; mf < 4; ++mf)
#pragma unroll
                for (int nf = 0; nf < 4; ++nf)
                    acc[mf][nf] = __builtin_amdgcn_mfma_f32_16x16x32_bf16(af[mf], bfr[nf], acc[mf][nf], 0, 0, 0);
        }
    }
#pragma unroll
    for (int mf = 0; mf < 4; ++mf)
#pragma unroll
        for (int nf = 0; nf < 4; ++nf) {
            int col = rowB0 + wc * 64 + nf * 16 + c;
            float bvv = bias[col];
#pragma unroll
            for (int j = 0; j < 4; ++j) {
                int row = rowA0 + wr * 64 + mf * 16 + g * 4 + j;
                out[(size_t)row * N + col] = acc[mf][nf][j] + bvv;
            }
        }
}

// ---------------- flash attention: r15 version (256 thr, u=2, static-max, ones-MFMA) ----------------
__global__ __launch_bounds__(256, 4)
void flash_kernel(const unsigned short* __restrict__ qbf,   // [B][T][D], pre-scaled log2e/8
                  const unsigned short* __restrict__ kbf,   // [B][T][D]
                  const unsigned short* __restrict__ vT,    // [B][H][HD][T] s-permuted
                  unsigned short* __restrict__ ohbf,        // [B][T][D]
                  float* __restrict__ madjOut) {            // [B][H][T]: 4 + log2(l)
    __shared__ unsigned short sK[2][64 * 64];    // dbuf, 2x8KB
    __shared__ unsigned short sV[2][64 * 64];    // dbuf, 2x8KB
    const int tid = threadIdx.x, lane = tid & 63, w = tid >> 6;
    const int c = lane & 15, g = lane >> 4;
    const int nb = (blockIdx.x & 7) * 128 + (blockIdx.x >> 3);
    const int t0 = (nb & 15) * 128, h = (nb >> 4) & 15, b = nb >> 8;

    bf16x8 qf[2][2];
#pragma unroll
    for (int u = 0; u < 2; ++u) {
        const size_t qbase = ((size_t)(b * T_) + t0 + w * 32 + u * 16 + c) * D_ + h * HD_;
        qf[u][0] = *reinterpret_cast<const bf16x8*>(qbf + qbase + g * 8);
        qf[u][1] = *reinterpret_cast<const bf16x8*>(qbf + qbase + 32 + g * 8);
    }

    const unsigned short one_bf = 0x3F80;
    const bf16x8 ones = { (short)one_bf, (short)one_bf, (short)one_bf, (short)one_bf,
                          (short)one_bf, (short)one_bf, (short)one_bf, (short)one_bf };

    f32x4 acc[2][4] = {};    // O numerator
    f32x4 acc_l[2] = {};     // l via ones-column; acc_l[u][j] = l for row g*4+j

    const unsigned short* kRow = kbf + (size_t)b * T_ * D_ + h * HD_;
    const unsigned short* vRow = vT + ((size_t)(b * H_ + h)) * HD_ * T_;

    auto stage = [&](int buf, int s0) {
#pragma unroll
        for (int i = 0; i < 2; ++i) {
            int chunk = tid + i * 256;
            int row = chunk >> 3, c16 = chunk & 7;
            int sc16 = c16 ^ (row & 7);
            gll16(kRow + (size_t)(s0 + row) * D_ + sc16 * 8, (char*)sK[buf] + chunk * 16);
            gll16(vRow + (size_t)row * T_ + s0 + sc16 * 8, (char*)sV[buf] + chunk * 16);
        }
    };

    stage(0, 0);   // L_0 in flight
    constexpr int NT = T_ / 64;

    for (int it = 0; it < NT; ++it) {
        const int cur = it & 1;
        if (it + 1 < NT) {
            stage(cur ^ 1, (it + 1) * 64);   // issue L_{it+1} (4 loads)
            asm volatile("s_waitcnt vmcnt(4)" ::: "memory");  // wait L_it only
        } else {
            asm volatile("s_waitcnt vmcnt(0)" ::: "memory");
        }
        RAW_BAR();                           // buf[cur] fully staged for all waves

        const char* sKc = (const char*)sK[cur];
        const char* sVc = (const char*)sV[cur];

        f32x4 sc[2][4] = {};
        __builtin_amdgcn_s_setprio(1);
#pragma unroll
        for (int kk = 0; kk < 2; ++kk)
#pragma unroll
            for (int nf = 0; nf < 4; ++nf) {
                int row = nf * 16 + c;
                int off = (row * 128 + kk * 64 + g * 16) ^ ((row & 7) << 4);
                bf16x8 kf = *reinterpret_cast<const bf16x8*>(sKc + off);
                sc[0][nf] = __builtin_amdgcn_mfma_f32_16x16x32_bf16(kf, qf[0][kk], sc[0][nf], 0, 0, 0);
                sc[1][nf] = __builtin_amdgcn_mfma_f32_16x16x32_bf16(kf, qf[1][kk], sc[1][nf], 0, 0, 0);
            }
        __builtin_amdgcn_s_setprio(0);

        // static-max softmax: p = exp2(s), no branch, no reductions
        u32x4 pkw[2][2];
#pragma unroll
        for (int u = 0; u < 2; ++u) {
#pragma unroll
            for (int nf = 0; nf < 4; ++nf)
#pragma unroll
                for (int j = 0; j < 4; ++j)
                    sc[u][nf][j] = fexp2(sc[u][nf][j]);
#pragma unroll
            for (int kk = 0; kk < 2; ++kk) {
                u32x4 pw;
                pw.x = cvt_pk_bf16(sc[u][2 * kk][0], sc[u][2 * kk][1]);
                pw.y = cvt_pk_bf16(sc[u][2 * kk][2], sc[u][2 * kk][3]);
                pw.z = cvt_pk_bf16(sc[u][2 * kk + 1][0], sc[u][2 * kk + 1][1]);
                pw.w = cvt_pk_bf16(sc[u][2 * kk + 1][2], sc[u][2 * kk + 1][3]);
                pkw[u][kk] = pw;
            }
        }

        __builtin_amdgcn_s_setprio(1);
#pragma unroll
        for (int kk = 0; kk < 2; ++kk) {
            bf16x8 pa0 = __builtin_bit_cast(bf16x8, pkw[0][kk]);
            bf16x8 pa1 = __builtin_bit_cast(bf16x8, pkw[1][kk]);
#pragma unroll
            for (int nf = 0; nf < 4; ++nf) {
                int row = nf * 16 + c;
                int voff = (row * 128 + kk * 64 + g * 16) ^ ((row & 7) << 4);
                bf16x8 vf = *reinterpret_cast<const bf16x8*>(sVc + voff);
                acc[0][nf] = __builtin_amdgcn_mfma_f32_16x16x32_bf16(pa0, vf, acc[0][nf], 0, 0, 0);
                acc[1][nf] = __builtin_amdgcn_mfma_f32_16x16x32_bf16(pa1, vf, acc[1][nf], 0, 0, 0);
            }
            // l accumulation: ones-column MFMA (row sums, lane-local result)
            acc_l[0] = __builtin_amdgcn_mfma_f32_16x16x32_bf16(pa0, ones, acc_l[0], 0, 0, 0);
            acc_l[1] = __builtin_amdgcn_mfma_f32_16x16x32_bf16(pa1, ones, acc_l[1], 0, 0, 0);
        }
        __builtin_amdgcn_s_setprio(0);
        RAW_BAR();   // all waves done reading buf[cur] before it is re-staged
    }

#pragma unroll
    for (int u = 0; u < 2; ++u) {
#pragma unroll
        for (int j = 0; j < 4; ++j) {
            float inv = 1.f / acc_l[u][j];     // lane-local: l for row g*4+j
            int trow = t0 + w * 32 + u * 16 + g * 4 + j;
#pragma unroll
            for (int nf = 0; nf < 4; ++nf)
                ohbf[((size_t)(b * T_) + trow) * D_ + h * HD_ + nf * 16 + c] = f2bf(acc[u][nf][j] * inv);
            if (c == 0)
                madjOut[((size_t)(b * H_ + h)) * T_ + trow] = 4.0f + __log2f(acc_l[u][j]);
        }
    }
}

// ---------------- weight: 512 threads, t128 x s128 tile, madj via LDS ----------------
__global__ __launch_bounds__(512, 4)
void weight_kernel(const unsigned short* __restrict__ qbf,
                   const unsigned short* __restrict__ kbf,
                   const float* __restrict__ madjIn,
                   float* __restrict__ wout) {
    __shared__ unsigned short sQ[2][128 * 64];   // dbuf, 2x16KB
    __shared__ unsigned short sK2[2][128 * 64];  // dbuf, 2x16KB
    __shared__ float sMadj[16][128];             // 8KB
    const int tid = threadIdx.x, lane = tid & 63, w = tid >> 6;  // w in [0,8)
    const int c = lane & 15, g = lane >> 4;
    const int wr = w >> 2, wc = w & 3;   // wave grid: 2 (t) x 4 (s)
    // XCD swizzle: 1024 blocks -> 128 contiguous per XCD
    const int nb = (blockIdx.x & 7) * 128 + (blockIdx.x >> 3);
    const int s0 = (nb & 15) * 128, t0 = ((nb >> 4) & 15) * 128, b = nb >> 8;

    float wacc[4][2][4] = {};

    auto stageW = [&](int buf, int h) {
#pragma unroll
        for (int i = 0; i < 2; ++i) {
            int chunk = tid + i * 512;        // 0..1023 (Q: 128 rows x 64)
            int row = chunk >> 3, c16 = chunk & 7;
            int sc16 = c16 ^ (row & 7);
            gll16(qbf + ((size_t)(b * T_) + t0 + row) * D_ + h * HD_ + sc16 * 8,
                  (char*)sQ[buf] + chunk * 16);
        }
#pragma unroll
        for (int i = 0; i < 2; ++i) {
            int chunk = tid + i * 512;        // 0..1023 (K: 128 rows x 64)
            int row = chunk >> 3, c16 = chunk & 7;
            int sc16 = c16 ^ (row & 7);
            gll16(kbf + ((size_t)(b * T_) + s0 + row) * D_ + h * HD_ + sc16 * 8,
                  (char*)sK2[buf] + chunk * 16);
        }
    };

    // one-time: preload madj[16 heads][128 t-rows] into LDS (coalesced float4/thread)
    {
        int hh = tid >> 5, tq = tid & 31;
        float4 mv = *reinterpret_cast<const float4*>(
            &madjIn[((size_t)(b * H_ + hh)) * T_ + t0 + tq * 4]);
        *reinterpret_cast<float4*>(&sMadj[hh][tq * 4]) = mv;
    }
    __syncthreads();

    stageW(0, 0);   // L_0 in flight (4 loads/thread)

    for (int h = 0; h < H_; ++h) {
        const int cur = h & 1;
        if (h + 1 < H_) {
            stageW(cur ^ 1, h + 1);          // issue L_{h+1} (4 loads)
            asm volatile("s_waitcnt vmcnt(4)" ::: "memory");  // wait L_h only
        } else {
            asm volatile("s_waitcnt vmcnt(0)" ::: "memory");
        }
        RAW_BAR();

        const char* sQc = (const char*)sQ[cur];
        const char* sKc = (const char*)sK2[cur];

        // C-init = -madj[h][local trow] from LDS
        f32x4 sc[4][2];
#pragma unroll
        for (int mf = 0; mf < 4; ++mf) {
            f32x4 mrow = *reinterpret_cast<const f32x4*>(&sMadj[h][wr * 64 + mf * 16 + g * 4]);
#pragma unroll
            for (int j = 0; j < 4; ++j) {
                sc[mf][0][j] = -mrow[j];
                sc[mf][1][j] = -mrow[j];
            }
        }

        __builtin_amdgcn_s_setprio(1);
#pragma unroll
        for (int kk = 0; kk < 2; ++kk) {
            bf16x8 af[4], bfr[2];
#pragma unroll
            for (int mf = 0; mf < 4; ++mf) {
                int row = wr * 64 + mf * 16 + c;
                int off = (row * 128 + kk * 64 + g * 16) ^ ((row & 7) << 4);
                af[mf] = *reinterpret_cast<const bf16x8*>(sQc + off);
            }
#pragma unroll
            for (int nf = 0; nf < 2; ++nf) {
                int row = wc * 32 + nf * 16 + c;
                int off = (row * 128 + kk * 64 + g * 16) ^ ((row & 7) << 4);
                bfr[nf] = *reinterpret_cast<const bf16x8*>(sKc + off);
            }
#pragma unroll
            for (int mf = 0; mf < 4; ++mf)
#pragma unroll
                for (int nf = 0; nf < 2; ++nf)
                    sc[mf][nf] = __builtin_amdgcn_mfma_f32_16x16x32_bf16(af[mf], bfr[nf], sc[mf][nf], 0, 0, 0);
        }
        __builtin_amdgcn_s_setprio(0);
#pragma unroll
        for (int mf = 0; mf < 4; ++mf)
#pragma unroll
            for (int nf = 0; nf < 2; ++nf)
#pragma unroll
                for (int j = 0; j < 4; ++j)
                    wacc[mf][nf][j] += fexp2(sc[mf][nf][j]);
        RAW_BAR();
    }
#pragma unroll
    for (int mf = 0; mf < 4; ++mf)
#pragma unroll
        for (int j = 0; j < 4; ++j) {
            int trow = t0 + wr * 64 + mf * 16 + g * 4 + j;
#pragma unroll
            for (int nf = 0; nf < 2; ++nf) {
                int col = s0 + wc * 32 + nf * 16 + c;
                wout[((size_t)b * T_ + trow) * (size_t)T_ + col] = wacc[mf][nf][j];
            }
        }
}

extern "C" void kernel_launch(void* const* d_in, const int* in_sizes, int n_in,
                              void* d_out, int out_size, void* d_ws, size_t ws_size,
                              hipStream_t stream) {
    const float* Q  = (const float*)d_in[0];
    const float* K  = (const float*)d_in[1];
    const float* V  = (const float*)d_in[2];
    const float* Wq = (const float*)d_in[3];
    const float* bq = (const float*)d_in[4];
    const float* Wk = (const float*)d_in[5];
    const float* bk = (const float*)d_in[6];
    const float* Wv = (const float*)d_in[7];
    const float* bv = (const float*)d_in[8];
    const float* Wo = (const float*)d_in[9];
    const float* bo = (const float*)d_in[10];

    char* ws = (char*)d_ws;
    const size_t MB = 1u << 20;
    unsigned short* Wqb = (unsigned short*)(ws);
    unsigned short* Wkb = Wqb + 1024 * 1024;
    unsigned short* Wvb = Wkb + 1024 * 1024;
    unsigned short* Wob = Wvb + 1024 * 1024;                 // ends @8MB
    unsigned short* ohb = (unsigned short*)(ws + 24 * MB);   // 16MB
    unsigned short* qb  = (unsigned short*)(ws + 56 * MB);   // 16MB
    unsigned short* kb  = (unsigned short*)(ws + 72 * MB);   // 16MB
    unsigned short* vT  = (unsigned short*)(ws + 88 * MB);   // 16MB (direct from gemm_qkv)
    float* mArr = (float*)(ws + 104 * MB);                   // 512KB (madj)

    cast_fused<<<dim3(256, 4), 256, 0, stream>>>(Wq, Wk, Wv, Wo, Wqb, Wkb, Wvb, Wob);

    gemm_qkv<<<dim3(8, 64, 3), 256, 0, stream>>>(Q, K, V, Wqb, Wkb, Wvb,
                                                 bq, bk, bv, qb, kb, vT);

    flash_kernel<<<1024, 256, 0, stream>>>(qb, kb, vT, ohb, mArr);

    float* Oout = (float*)d_out;
    float* Wout = Oout + (size_t)BT_ * D_;
    gemm_o<<<dim3(8, 64), 256, 0, stream>>>(ohb, Wob, bo, Oout);
    weight_kernel<<<1024, 512, 0, stream>>>(qb, kb, mArr, Wout);
}

// Round 19
// 252.601 us; speedup vs baseline: 1.0015x; 1.0015x over previous
//
#include <hip/hip_runtime.h>
#include <stdint.h>

typedef __attribute__((ext_vector_type(8))) short bf16x8;
typedef __attribute__((ext_vector_type(4))) float f32x4;
typedef __attribute__((ext_vector_type(4))) unsigned int u32x4;

static constexpr int B_ = 4, T_ = 2048, D_ = 1024, H_ = 16, HD_ = 64;
static constexpr int BT_ = B_ * T_;
static constexpr float LOG2E_OVER_8 = 0.18033688011112042f;  // log2(e)/8

#define DEV static __device__ __forceinline__

// raw barrier with scheduling fences (no vmcnt drain, unlike __syncthreads)
#define RAW_BAR() do { \
    __builtin_amdgcn_sched_barrier(0); \
    __builtin_amdgcn_s_barrier(); \
    __builtin_amdgcn_sched_barrier(0); \
} while (0)

DEV unsigned short f2bf(float f) {
    union { float f; uint32_t u; } v; v.f = f;
    uint32_t u = v.u;
    uint32_t r = (u + 0x7fffu + ((u >> 16) & 1u)) >> 16;  // RN-even
    return (unsigned short)r;
}

DEV uint32_t cvt_pk_bf16(float lo, float hi) {
    uint32_t r;
    asm("v_cvt_pk_bf16_f32 %0, %1, %2" : "=v"(r) : "v"(lo), "v"(hi));
    return r;
}

DEV float fexp2(float x) {   // raw v_exp_f32 (2^x)
    float r;
    asm("v_exp_f32 %0, %1" : "=v"(r) : "v"(x));
    return r;
}

DEV void gll16(const void* g, void* l) {
    __builtin_amdgcn_global_load_lds(
        (const __attribute__((address_space(1))) void*)g,
        (__attribute__((address_space(3))) void*)l, 16, 0, 0);
}

// ---------------- fused cast fp32 -> bf16: all 7 arrays, grid.y selects ----------------
__global__ __launch_bounds__(256)
void cast_fused(const float* __restrict__ q, const float* __restrict__ k, const float* __restrict__ v,
                const float* __restrict__ wq, const float* __restrict__ wk,
                const float* __restrict__ wv, const float* __restrict__ wo,
                unsigned short* __restrict__ oq, unsigned short* __restrict__ ok,
                unsigned short* __restrict__ ov, unsigned short* __restrict__ owq,
                unsigned short* __restrict__ owk, unsigned short* __restrict__ owv,
                unsigned short* __restrict__ owo) {
    const int y = blockIdx.y;
    const float* s; unsigned short* d; int n4;
    switch (y) {
        case 0: s = q;  d = oq;  n4 = BT_ * D_ / 4; break;
        case 1: s = k;  d = ok;  n4 = BT_ * D_ / 4; break;
        case 2: s = v;  d = ov;  n4 = BT_ * D_ / 4; break;
        case 3: s = wq; d = owq; n4 = D_ * D_ / 4; break;
        case 4: s = wk; d = owk; n4 = D_ * D_ / 4; break;
        case 5: s = wv; d = owv; n4 = D_ * D_ / 4; break;
        default: s = wo; d = owo; n4 = D_ * D_ / 4; break;
    }
    for (int i = blockIdx.x * blockDim.x + threadIdx.x; i < n4; i += gridDim.x * blockDim.x) {
        float4 vv = reinterpret_cast<const float4*>(s)[i];
        ushort4 o;
        o.x = f2bf(vv.x); o.y = f2bf(vv.y); o.z = f2bf(vv.z); o.w = f2bf(vv.w);
        reinterpret_cast<ushort4*>(d)[i] = o;
    }
}

// ---------------- fused QKV projection GEMM (single-buffer m97 structure, XCD swizzle) ----------------
// z==0: q out (scaled log2e/8), z==1: k out, z==2: V out written DIRECTLY to vT
__global__ __launch_bounds__(256, 4)
void gemm_qkv(const unsigned short* __restrict__ Aq, const unsigned short* __restrict__ Ak,
              const unsigned short* __restrict__ Av,
              const unsigned short* __restrict__ Wqb, const unsigned short* __restrict__ Wkb,
              const unsigned short* __restrict__ Wvb,
              const float* __restrict__ bq, const float* __restrict__ bk,
              const float* __restrict__ bv,
              unsigned short* __restrict__ oq, unsigned short* __restrict__ ok,
              unsigned short* __restrict__ vT) {
    constexpr int K = 1024, N = 1024, BK = 64;
    __shared__ unsigned short sA[128 * BK];   // 16KB
    __shared__ unsigned short sB[128 * BK];   // 16KB
    // XCD swizzle: 1536 blocks -> 192 contiguous (z,bm,bn) per XCD; A-panels XCD-local
    const int flat = blockIdx.x + (blockIdx.y << 3) + (blockIdx.z << 9);
    const int nbz = (flat & 7) * 192 + (flat >> 3);
    const int z = nbz >> 9;
    const int rem = nbz & 511;
    const int bm = rem >> 3, bn = rem & 7;

    const unsigned short* A = z == 0 ? Aq : z == 1 ? Ak : Av;
    const unsigned short* W = z == 0 ? Wqb : z == 1 ? Wkb : Wvb;
    const float* bias        = z == 0 ? bq : z == 1 ? bk : bv;
    const float oscale       = z == 0 ? LOG2E_OVER_8 : 1.0f;

    const int tid = threadIdx.x;
    const int lane = tid & 63, w = tid >> 6;
    const int c = lane & 15, g = lane >> 4;
    const int wr = w >> 1, wc = w & 1;
    const int rowA0 = bm * 128, rowB0 = bn * 128;

    f32x4 acc[4][4] = {};

    for (int k0 = 0; k0 < K; k0 += BK) {
        __syncthreads();
#pragma unroll
        for (int i = 0; i < 4; ++i) {
            int chunk = tid + i * 256;          // 0..1023
            int row = chunk >> 3, c16 = chunk & 7;
            int sc16 = c16 ^ (row & 7);          // source-side swizzle
            gll16(A + (size_t)(rowA0 + row) * K + k0 + sc16 * 8, (char*)sA + chunk * 16);
            gll16(W + (size_t)(rowB0 + row) * K + k0 + sc16 * 8, (char*)sB + chunk * 16);
        }
        __syncthreads();
#pragma unroll
        for (int kk = 0; kk < 2; ++kk) {
            bf16x8 af[4], bfr[4];
#pragma unroll
            for (int mf = 0; mf < 4; ++mf) {
                int row = wr * 64 + mf * 16 + c;
                int off = (row * 128 + kk * 64 + g * 16) ^ ((row & 7) << 4);
                af[mf] = *reinterpret_cast<const bf16x8*>((const char*)sA + off);
            }
#pragma unroll
            for (int nf = 0; nf < 4; ++nf) {
                int row = wc * 64 + nf * 16 + c;
                int off = (row * 128 + kk * 64 + g * 16) ^ ((row & 7) << 4);
                bfr[nf] = *reinterpret_cast<const bf16x8*>((const char*)sB + off);
            }
#pragma unroll
            for (int mf = 0; mf < 4; ++mf)
#pragma unroll
                for (int nf = 0; nf < 4; ++nf)
                    acc[mf][nf] = __builtin_amdgcn_mfma_f32_16x16x32_bf16(af[mf], bfr[nf], acc[mf][nf], 0, 0, 0);
        }
    }

    if (z == 2) {
        // direct transposed+permuted write into vT[b][h][d][t]
#pragma unroll
        for (int mf = 0; mf < 4; ++mf) {
            int rowbase = rowA0 + wr * 64 + mf * 16 + g * 4;   // multiple of 4
            int bb = rowbase >> 11;
            int trow = rowbase & 2047;
            int blk = trow >> 6, off = trow & 63;              // off multiple of 4
            int slot = (off & 32) | ((off & 8) << 1) | ((off & 4) << 1) | ((off & 16) >> 2);
#pragma unroll
            for (int nf = 0; nf < 4; ++nf) {
                int col = rowB0 + wc * 64 + nf * 16 + c;       // = h*64 + d
                float bvv = bias[col];
                int hh = col >> 6, d = col & 63;
                ushort4 o;
                o.x = f2bf(acc[mf][nf][0] + bvv);
                o.y = f2bf(acc[mf][nf][1] + bvv);
                o.z = f2bf(acc[mf][nf][2] + bvv);
                o.w = f2bf(acc[mf][nf][3] + bvv);
                size_t addr = (((size_t)(bb * H_ + hh)) * HD_ + d) * T_ + blk * 64 + slot;
                *reinterpret_cast<ushort4*>(&vT[addr]) = o;
            }
        }
    } else {
        unsigned short* out = z == 0 ? oq : ok;
#pragma unroll
        for (int mf = 0; mf < 4; ++mf)
#pragma unroll
            for (int nf = 0; nf < 4; ++nf) {
                int col = rowB0 + wc * 64 + nf * 16 + c;
                float bvv = bias[col];
#pragma unroll
                for (int j = 0; j < 4; ++j) {
                    int row = rowA0 + wr * 64 + mf * 16 + g * 4 + j;
                    float v = (acc[mf][nf][j] + bvv) * oscale;
                    out[(size_t)row * N + col] = f2bf(v);
                }
            }
    }
}

// ---------------- O projection GEMM (fp32 out, single-buffer, XCD swizzle) ----------------
__global__ __launch_bounds__(256, 4)
void gemm_o(const unsigned short* __restrict__ A, const unsigned short* __restrict__ W,
            const float* __restrict__ bias, float* __restrict__ out) {
    constexpr int K = 1024, N = 1024, BK = 64;
    __shared__ unsigned short sA[128 * BK];
    __shared__ unsigned short sB[128 * BK];
    const int tid = threadIdx.x;
    const int lane = tid & 63, w = tid >> 6;
    const int c = lane & 15, g = lane >> 4;
    // XCD swizzle: 512 blocks -> 64 contiguous (bm,bn) per XCD
    const int flat = blockIdx.x + (blockIdx.y << 3);
    const int nbz = (flat & 7) * 64 + (flat >> 3);
    const int bm = nbz >> 3, bn = nbz & 7;
    const int wr = w >> 1, wc = w & 1;
    const int rowA0 = bm * 128, rowB0 = bn * 128;

    f32x4 acc[4][4] = {};

    for (int k0 = 0; k0 < K; k0 += BK) {
        __syncthreads();
#pragma unroll
        for (int i = 0; i < 4; ++i) {
            int chunk = tid + i * 256;
            int row = chunk >> 3, c16 = chunk & 7;
            int sc16 = c16 ^ (row & 7);
            gll16(A + (size_t)(rowA0 + row) * K + k0 + sc16 * 8, (char*)sA + chunk * 16);
            gll16(W + (size_t)(rowB0 + row) * K + k0 + sc16 * 8, (char*)sB + chunk * 16);
        }
        __syncthreads();
#pragma unroll
        for (int kk = 0; kk < 2; ++kk) {
            bf16x8 af[4], bfr[4];
#pragma unroll
            for (int mf = 0; mf < 4; ++mf) {
                int row = wr * 64 + mf * 16 + c;
                int off = (row * 128 + kk * 64 + g * 16) ^ ((row & 7) << 4);
                af[mf] = *reinterpret_cast<const bf16x8*>((const char*)sA + off);
            }
#pragma unroll
            for (int nf = 0; nf < 4; ++nf) {
                int row = wc * 64 + nf * 16 + c;
                int off = (row * 128 + kk * 64 + g * 16) ^ ((row & 7) << 4);
                bfr[nf] = *reinterpret_cast<const bf16x8*>((const char*)sB + off);
            }
#pragma unroll
            for (int mf = 0; mf < 4; ++mf)
#pragma unroll
                for (int nf = 0; nf < 4; ++nf)
                    acc[mf][nf] = __builtin_amdgcn_mfma_f32_16x16x32_bf16(af[mf], bfr[nf], acc[mf][nf], 0, 0, 0);
        }
    }
#pragma unroll
    for (int mf = 0; mf < 4; ++mf)
#pragma unroll
        for (int nf = 0; nf < 4; ++nf) {
            int col = rowB0 + wc * 64 + nf * 16 + c;
            float bvv = bias[col];
#pragma unroll
            for (int j = 0; j < 4; ++j) {
                int row = rowA0 + wr * 64 + mf * 16 + g * 4 + j;
                out[(size_t)row * N + col] = acc[mf][nf][j] + bvv;
            }
        }
}

// ---------------- flash attention: r15 version (256 thr, u=2, static-max, ones-MFMA) ----------------
__global__ __launch_bounds__(256, 4)
void flash_kernel(const unsigned short* __restrict__ qbf,   // [B][T][D], pre-scaled log2e/8
                  const unsigned short* __restrict__ kbf,   // [B][T][D]
                  const unsigned short* __restrict__ vT,    // [B][H][HD][T] s-permuted
                  unsigned short* __restrict__ ohbf,        // [B][T][D]
                  float* __restrict__ madjOut) {            // [B][H][T]: 4 + log2(l)
    __shared__ unsigned short sK[2][64 * 64];    // dbuf, 2x8KB
    __shared__ unsigned short sV[2][64 * 64];    // dbuf, 2x8KB
    const int tid = threadIdx.x, lane = tid & 63, w = tid >> 6;
    const int c = lane & 15, g = lane >> 4;
    const int nb = (blockIdx.x & 7) * 128 + (blockIdx.x >> 3);
    const int t0 = (nb & 15) * 128, h = (nb >> 4) & 15, b = nb >> 8;

    bf16x8 qf[2][2];
#pragma unroll
    for (int u = 0; u < 2; ++u) {
        const size_t qbase = ((size_t)(b * T_) + t0 + w * 32 + u * 16 + c) * D_ + h * HD_;
        qf[u][0] = *reinterpret_cast<const bf16x8*>(qbf + qbase + g * 8);
        qf[u][1] = *reinterpret_cast<const bf16x8*>(qbf + qbase + 32 + g * 8);
    }

    const unsigned short one_bf = 0x3F80;
    const bf16x8 ones = { (short)one_bf, (short)one_bf, (short)one_bf, (short)one_bf,
                          (short)one_bf, (short)one_bf, (short)one_bf, (short)one_bf };

    f32x4 acc[2][4] = {};    // O numerator
    f32x4 acc_l[2] = {};     // l via ones-column; acc_l[u][j] = l for row g*4+j

    const unsigned short* kRow = kbf + (size_t)b * T_ * D_ + h * HD_;
    const unsigned short* vRow = vT + ((size_t)(b * H_ + h)) * HD_ * T_;

    auto stage = [&](int buf, int s0) {
#pragma unroll
        for (int i = 0; i < 2; ++i) {
            int chunk = tid + i * 256;
            int row = chunk >> 3, c16 = chunk & 7;
            int sc16 = c16 ^ (row & 7);
            gll16(kRow + (size_t)(s0 + row) * D_ + sc16 * 8, (char*)sK[buf] + chunk * 16);
            gll16(vRow + (size_t)row * T_ + s0 + sc16 * 8, (char*)sV[buf] + chunk * 16);
        }
    };

    stage(0, 0);   // L_0 in flight
    constexpr int NT = T_ / 64;

    for (int it = 0; it < NT; ++it) {
        const int cur = it & 1;
        if (it + 1 < NT) {
            stage(cur ^ 1, (it + 1) * 64);   // issue L_{it+1} (4 loads)
            asm volatile("s_waitcnt vmcnt(4)" ::: "memory");  // wait L_it only
        } else {
            asm volatile("s_waitcnt vmcnt(0)" ::: "memory");
        }
        RAW_BAR();                           // buf[cur] fully staged for all waves

        const char* sKc = (const char*)sK[cur];
        const char* sVc = (const char*)sV[cur];

        f32x4 sc[2][4] = {};
        __builtin_amdgcn_s_setprio(1);
#pragma unroll
        for (int kk = 0; kk < 2; ++kk)
#pragma unroll
            for (int nf = 0; nf < 4; ++nf) {
                int row = nf * 16 + c;
                int off = (row * 128 + kk * 64 + g * 16) ^ ((row & 7) << 4);
                bf16x8 kf = *reinterpret_cast<const bf16x8*>(sKc + off);
                sc[0][nf] = __builtin_amdgcn_mfma_f32_16x16x32_bf16(kf, qf[0][kk], sc[0][nf], 0, 0, 0);
                sc[1][nf] = __builtin_amdgcn_mfma_f32_16x16x32_bf16(kf, qf[1][kk], sc[1][nf], 0, 0, 0);
            }
        __builtin_amdgcn_s_setprio(0);

        // static-max softmax: p = exp2(s), no branch, no reductions
        u32x4 pkw[2][2];
#pragma unroll
        for (int u = 0; u < 2; ++u) {
#pragma unroll
            for (int nf = 0; nf < 4; ++nf)
#pragma unroll
                for (int j = 0; j < 4; ++j)
                    sc[u][nf][j] = fexp2(sc[u][nf][j]);
#pragma unroll
            for (int kk = 0; kk < 2; ++kk) {
                u32x4 pw;
                pw.x = cvt_pk_bf16(sc[u][2 * kk][0], sc[u][2 * kk][1]);
                pw.y = cvt_pk_bf16(sc[u][2 * kk][2], sc[u][2 * kk][3]);
                pw.z = cvt_pk_bf16(sc[u][2 * kk + 1][0], sc[u][2 * kk + 1][1]);
                pw.w = cvt_pk_bf16(sc[u][2 * kk + 1][2], sc[u][2 * kk + 1][3]);
                pkw[u][kk] = pw;
            }
        }

        __builtin_amdgcn_s_setprio(1);
#pragma unroll
        for (int kk = 0; kk < 2; ++kk) {
            bf16x8 pa0 = __builtin_bit_cast(bf16x8, pkw[0][kk]);
            bf16x8 pa1 = __builtin_bit_cast(bf16x8, pkw[1][kk]);
#pragma unroll
            for (int nf = 0; nf < 4; ++nf) {
                int row = nf * 16 + c;
                int voff = (row * 128 + kk * 64 + g * 16) ^ ((row & 7) << 4);
                bf16x8 vf = *reinterpret_cast<const bf16x8*>(sVc + voff);
                acc[0][nf] = __builtin_amdgcn_mfma_f32_16x16x32_bf16(pa0, vf, acc[0][nf], 0, 0, 0);
                acc[1][nf] = __builtin_amdgcn_mfma_f32_16x16x32_bf16(pa1, vf, acc[1][nf], 0, 0, 0);
            }
            // l accumulation: ones-column MFMA (row sums, lane-local result)
            acc_l[0] = __builtin_amdgcn_mfma_f32_16x16x32_bf16(pa0, ones, acc_l[0], 0, 0, 0);
            acc_l[1] = __builtin_amdgcn_mfma_f32_16x16x32_bf16(pa1, ones, acc_l[1], 0, 0, 0);
        }
        __builtin_amdgcn_s_setprio(0);
        RAW_BAR();   // all waves done reading buf[cur] before it is re-staged
    }

#pragma unroll
    for (int u = 0; u < 2; ++u) {
#pragma unroll
        for (int j = 0; j < 4; ++j) {
            float inv = 1.f / acc_l[u][j];     // lane-local: l for row g*4+j
            int trow = t0 + w * 32 + u * 16 + g * 4 + j;
#pragma unroll
            for (int nf = 0; nf < 4; ++nf)
                ohbf[((size_t)(b * T_) + trow) * D_ + h * HD_ + nf * 16 + c] = f2bf(acc[u][nf][j] * inv);
            if (c == 0)
                madjOut[((size_t)(b * H_ + h)) * T_ + trow] = 4.0f + __log2f(acc_l[u][j]);
        }
    }
}

// ---------------- weight: 512 threads, t128 x s128 tile, madj via LDS ----------------
__global__ __launch_bounds__(512, 4)
void weight_kernel(const unsigned short* __restrict__ qbf,
                   const unsigned short* __restrict__ kbf,
                   const float* __restrict__ madjIn,
                   float* __restrict__ wout) {
    __shared__ unsigned short sQ[2][128 * 64];   // dbuf, 2x16KB
    __shared__ unsigned short sK2[2][128 * 64];  // dbuf, 2x16KB
    __shared__ float sMadj[16][128];             // 8KB
    const int tid = threadIdx.x, lane = tid & 63, w = tid >> 6;  // w in [0,8)
    const int c = lane & 15, g = lane >> 4;
    const int wr = w >> 2, wc = w & 3;   // wave grid: 2 (t) x 4 (s)
    // XCD swizzle: 1024 blocks -> 128 contiguous per XCD
    const int nb = (blockIdx.x & 7) * 128 + (blockIdx.x >> 3);
    const int s0 = (nb & 15) * 128, t0 = ((nb >> 4) & 15) * 128, b = nb >> 8;

    float wacc[4][2][4] = {};

    auto stageW = [&](int buf, int h) {
#pragma unroll
        for (int i = 0; i < 2; ++i) {
            int chunk = tid + i * 512;        // 0..1023 (Q: 128 rows x 64)
            int row = chunk >> 3, c16 = chunk & 7;
            int sc16 = c16 ^ (row & 7);
            gll16(qbf + ((size_t)(b * T_) + t0 + row) * D_ + h * HD_ + sc16 * 8,
                  (char*)sQ[buf] + chunk * 16);
        }
#pragma unroll
        for (int i = 0; i < 2; ++i) {
            int chunk = tid + i * 512;        // 0..1023 (K: 128 rows x 64)
            int row = chunk >> 3, c16 = chunk & 7;
            int sc16 = c16 ^ (row & 7);
            gll16(kbf + ((size_t)(b * T_) + s0 + row) * D_ + h * HD_ + sc16 * 8,
                  (char*)sK2[buf] + chunk * 16);
        }
    };

    // one-time: preload madj[16 heads][128 t-rows] into LDS (coalesced float4/thread)
    {
        int hh = tid >> 5, tq = tid & 31;
        float4 mv = *reinterpret_cast<const float4*>(
            &madjIn[((size_t)(b * H_ + hh)) * T_ + t0 + tq * 4]);
        *reinterpret_cast<float4*>(&sMadj[hh][tq * 4]) = mv;
    }
    __syncthreads();

    stageW(0, 0);   // L_0 in flight (4 loads/thread)

    for (int h = 0; h < H_; ++h) {
        const int cur = h & 1;
        if (h + 1 < H_) {
            stageW(cur ^ 1, h + 1);          // issue L_{h+1} (4 loads)
            asm volatile("s_waitcnt vmcnt(4)" ::: "memory");  // wait L_h only
        } else {
            asm volatile("s_waitcnt vmcnt(0)" ::: "memory");
        }
        RAW_BAR();

        const char* sQc = (const char*)sQ[cur];
        const char* sKc = (const char*)sK2[cur];

        // C-init = -madj[h][local trow] from LDS
        f32x4 sc[4][2];
#pragma unroll
        for (int mf = 0; mf < 4; ++mf) {
            f32x4 mrow = *reinterpret_cast<const f32x4*>(&sMadj[h][wr * 64 + mf * 16 + g * 4]);
#pragma unroll
            for (int j = 0; j < 4; ++j) {
                sc[mf][0][j] = -mrow[j];
                sc[mf][1][j] = -mrow[j];
            }
        }

        __builtin_amdgcn_s_setprio(1);
#pragma unroll
        for (int kk = 0; kk < 2; ++kk) {
            bf16x8 af[4], bfr[2];
#pragma unroll
            for (int mf = 0; mf < 4; ++mf) {
                int row = wr * 64 + mf * 16 + c;
                int off = (row * 128 + kk * 64 + g * 16) ^ ((row & 7) << 4);
                af[mf] = *reinterpret_cast<const bf16x8*>(sQc + off);
            }
#pragma unroll
            for (int nf = 0; nf < 2; ++nf) {
                int row = wc * 32 + nf * 16 + c;
                int off = (row * 128 + kk * 64 + g * 16) ^ ((row & 7) << 4);
                bfr[nf] = *reinterpret_cast<const bf16x8*>(sKc + off);
            }
#pragma unroll
            for (int mf = 0; mf < 4; ++mf)
#pragma unroll
                for (int nf = 0; nf < 2; ++nf)
                    sc[mf][nf] = __builtin_amdgcn_mfma_f32_16x16x32_bf16(af[mf], bfr[nf], sc[mf][nf], 0, 0, 0);
        }
        __builtin_amdgcn_s_setprio(0);
#pragma unroll
        for (int mf = 0; mf < 4; ++mf)
#pragma unroll
            for (int nf = 0; nf < 2; ++nf)
#pragma unroll
                for (int j = 0; j < 4; ++j)
                    wacc[mf][nf][j] += fexp2(sc[mf][nf][j]);
        RAW_BAR();
    }
#pragma unroll
    for (int mf = 0; mf < 4; ++mf)
#pragma unroll
        for (int j = 0; j < 4; ++j) {
            int trow = t0 + wr * 64 + mf * 16 + g * 4 + j;
#pragma unroll
            for (int nf = 0; nf < 2; ++nf) {
                int col = s0 + wc * 32 + nf * 16 + c;
                wout[((size_t)b * T_ + trow) * (size_t)T_ + col] = wacc[mf][nf][j];
            }
        }
}

extern "C" void kernel_launch(void* const* d_in, const int* in_sizes, int n_in,
                              void* d_out, int out_size, void* d_ws, size_t ws_size,
                              hipStream_t stream) {
    const float* Q  = (const float*)d_in[0];
    const float* K  = (const float*)d_in[1];
    const float* V  = (const float*)d_in[2];
    const float* Wq = (const float*)d_in[3];
    const float* bq = (const float*)d_in[4];
    const float* Wk = (const float*)d_in[5];
    const float* bk = (const float*)d_in[6];
    const float* Wv = (const float*)d_in[7];
    const float* bv = (const float*)d_in[8];
    const float* Wo = (const float*)d_in[9];
    const float* bo = (const float*)d_in[10];

    char* ws = (char*)d_ws;
    const size_t MB = 1u << 20;
    unsigned short* Wqb = (unsigned short*)(ws);
    unsigned short* Wkb = Wqb + 1024 * 1024;
    unsigned short* Wvb = Wkb + 1024 * 1024;
    unsigned short* Wob = Wvb + 1024 * 1024;                 // ends @8MB
    unsigned short* Qc  = (unsigned short*)(ws + 8 * MB);    // 16MB
    unsigned short* Kc  = (unsigned short*)(ws + 24 * MB);   // 16MB
    unsigned short* Vc  = (unsigned short*)(ws + 40 * MB);   // 16MB
    unsigned short* qb  = (unsigned short*)(ws + 56 * MB);   // 16MB
    unsigned short* kb  = (unsigned short*)(ws + 72 * MB);   // 16MB
    unsigned short* vT  = (unsigned short*)(ws + 88 * MB);   // 16MB (direct from gemm_qkv)
    unsigned short* ohb = Kc;    // alias: Kc dead after gemm_qkv
    float* mArr = (float*)(ws + 104 * MB);                   // 512KB (madj)

    cast_fused<<<dim3(1024, 7), 256, 0, stream>>>(Q, K, V, Wq, Wk, Wv, Wo,
                                                  Qc, Kc, Vc, Wqb, Wkb, Wvb, Wob);

    gemm_qkv<<<dim3(8, 64, 3), 256, 0, stream>>>(Qc, Kc, Vc, Wqb, Wkb, Wvb,
                                                 bq, bk, bv, qb, kb, vT);

    flash_kernel<<<1024, 256, 0, stream>>>(qb, kb, vT, ohb, mArr);

    float* Oout = (float*)d_out;
    float* Wout = Oout + (size_t)BT_ * D_;
    gemm_o<<<dim3(8, 64), 256, 0, stream>>>(ohb, Wob, bo, Oout);
    weight_kernel<<<1024, 512, 0, stream>>>(qb, kb, mArr, Wout);
}

// Round 20
// 250.149 us; speedup vs baseline: 1.0113x; 1.0098x over previous
//
#include <hip/hip_runtime.h>
#include <stdint.h>

typedef __attribute__((ext_vector_type(8))) short bf16x8;
typedef __attribute__((ext_vector_type(4))) float f32x4;
typedef __attribute__((ext_vector_type(4))) unsigned int u32x4;

static constexpr int B_ = 4, T_ = 2048, D_ = 1024, H_ = 16, HD_ = 64;
static constexpr int BT_ = B_ * T_;
static constexpr float LOG2E_OVER_8 = 0.18033688011112042f;  // log2(e)/8

#define DEV static __device__ __forceinline__

// raw barrier with scheduling fences (no vmcnt drain, unlike __syncthreads)
#define RAW_BAR() do { \
    __builtin_amdgcn_sched_barrier(0); \
    __builtin_amdgcn_s_barrier(); \
    __builtin_amdgcn_sched_barrier(0); \
} while (0)

DEV unsigned short f2bf(float f) {
    union { float f; uint32_t u; } v; v.f = f;
    uint32_t u = v.u;
    uint32_t r = (u + 0x7fffu + ((u >> 16) & 1u)) >> 16;  // RN-even
    return (unsigned short)r;
}

DEV uint32_t cvt_pk_bf16(float lo, float hi) {
    uint32_t r;
    asm("v_cvt_pk_bf16_f32 %0, %1, %2" : "=v"(r) : "v"(lo), "v"(hi));
    return r;
}

DEV float fexp2(float x) {   // raw v_exp_f32 (2^x)
    float r;
    asm("v_exp_f32 %0, %1" : "=v"(r) : "v"(x));
    return r;
}

DEV void gll16(const void* g, void* l) {
    __builtin_amdgcn_global_load_lds(
        (const __attribute__((address_space(1))) void*)g,
        (__attribute__((address_space(3))) void*)l, 16, 0, 0);
}

// ---------------- fused cast fp32 -> bf16: all 7 arrays, grid.y selects ----------------
__global__ __launch_bounds__(256)
void cast_fused(const float* __restrict__ q, const float* __restrict__ k, const float* __restrict__ v,
                const float* __restrict__ wq, const float* __restrict__ wk,
                const float* __restrict__ wv, const float* __restrict__ wo,
                unsigned short* __restrict__ oq, unsigned short* __restrict__ ok,
                unsigned short* __restrict__ ov, unsigned short* __restrict__ owq,
                unsigned short* __restrict__ owk, unsigned short* __restrict__ owv,
                unsigned short* __restrict__ owo) {
    const int y = blockIdx.y;
    const float* s; unsigned short* d; int n4;
    switch (y) {
        case 0: s = q;  d = oq;  n4 = BT_ * D_ / 4; break;
        case 1: s = k;  d = ok;  n4 = BT_ * D_ / 4; break;
        case 2: s = v;  d = ov;  n4 = BT_ * D_ / 4; break;
        case 3: s = wq; d = owq; n4 = D_ * D_ / 4; break;
        case 4: s = wk; d = owk; n4 = D_ * D_ / 4; break;
        case 5: s = wv; d = owv; n4 = D_ * D_ / 4; break;
        default: s = wo; d = owo; n4 = D_ * D_ / 4; break;
    }
    for (int i = blockIdx.x * blockDim.x + threadIdx.x; i < n4; i += gridDim.x * blockDim.x) {
        float4 vv = reinterpret_cast<const float4*>(s)[i];
        ushort4 o;
        o.x = f2bf(vv.x); o.y = f2bf(vv.y); o.z = f2bf(vv.z); o.w = f2bf(vv.w);
        reinterpret_cast<ushort4*>(d)[i] = o;
    }
}

// ---------------- fused QKV projection GEMM (single-buffer m97 structure, XCD swizzle) ----------------
// z==0: q out (scaled log2e/8), z==1: k out, z==2: V out written DIRECTLY to vT
__global__ __launch_bounds__(256, 3)
void gemm_qkv(const unsigned short* __restrict__ Aq, const unsigned short* __restrict__ Ak,
              const unsigned short* __restrict__ Av,
              const unsigned short* __restrict__ Wqb, const unsigned short* __restrict__ Wkb,
              const unsigned short* __restrict__ Wvb,
              const float* __restrict__ bq, const float* __restrict__ bk,
              const float* __restrict__ bv,
              unsigned short* __restrict__ oq, unsigned short* __restrict__ ok,
              unsigned short* __restrict__ vT) {
    constexpr int K = 1024, N = 1024, BK = 64;
    __shared__ unsigned short sA[128 * BK];   // 16KB
    __shared__ unsigned short sB[128 * BK];   // 16KB
    // XCD swizzle: 1536 blocks -> 192 contiguous (z,bm,bn) per XCD; A-panels XCD-local
    const int flat = blockIdx.x + (blockIdx.y << 3) + (blockIdx.z << 9);
    const int nbz = (flat & 7) * 192 + (flat >> 3);
    const int z = nbz >> 9;
    const int rem = nbz & 511;
    const int bm = rem >> 3, bn = rem & 7;

    const unsigned short* A = z == 0 ? Aq : z == 1 ? Ak : Av;
    const unsigned short* W = z == 0 ? Wqb : z == 1 ? Wkb : Wvb;
    const float* bias        = z == 0 ? bq : z == 1 ? bk : bv;
    const float oscale       = z == 0 ? LOG2E_OVER_8 : 1.0f;

    const int tid = threadIdx.x;
    const int lane = tid & 63, w = tid >> 6;
    const int c = lane & 15, g = lane >> 4;
    const int wr = w >> 1, wc = w & 1;
    const int rowA0 = bm * 128, rowB0 = bn * 128;

    f32x4 acc[4][4] = {};

    for (int k0 = 0; k0 < K; k0 += BK) {
        __syncthreads();
#pragma unroll
        for (int i = 0; i < 4; ++i) {
            int chunk = tid + i * 256;          // 0..1023
            int row = chunk >> 3, c16 = chunk & 7;
            int sc16 = c16 ^ (row & 7);          // source-side swizzle
            gll16(A + (size_t)(rowA0 + row) * K + k0 + sc16 * 8, (char*)sA + chunk * 16);
            gll16(W + (size_t)(rowB0 + row) * K + k0 + sc16 * 8, (char*)sB + chunk * 16);
        }
        __syncthreads();
#pragma unroll
        for (int kk = 0; kk < 2; ++kk) {
            bf16x8 af[4], bfr[4];
#pragma unroll
            for (int mf = 0; mf < 4; ++mf) {
                int row = wr * 64 + mf * 16 + c;
                int off = (row * 128 + kk * 64 + g * 16) ^ ((row & 7) << 4);
                af[mf] = *reinterpret_cast<const bf16x8*>((const char*)sA + off);
            }
#pragma unroll
            for (int nf = 0; nf < 4; ++nf) {
                int row = wc * 64 + nf * 16 + c;
                int off = (row * 128 + kk * 64 + g * 16) ^ ((row & 7) << 4);
                bfr[nf] = *reinterpret_cast<const bf16x8*>((const char*)sB + off);
            }
#pragma unroll
            for (int mf = 0; mf < 4; ++mf)
#pragma unroll
                for (int nf = 0; nf < 4; ++nf)
                    acc[mf][nf] = __builtin_amdgcn_mfma_f32_16x16x32_bf16(af[mf], bfr[nf], acc[mf][nf], 0, 0, 0);
        }
    }

    if (z == 2) {
        // direct transposed+permuted write into vT[b][h][d][t]
#pragma unroll
        for (int mf = 0; mf < 4; ++mf) {
            int rowbase = rowA0 + wr * 64 + mf * 16 + g * 4;   // multiple of 4
            int bb = rowbase >> 11;
            int trow = rowbase & 2047;
            int blk = trow >> 6, off = trow & 63;              // off multiple of 4
            int slot = (off & 32) | ((off & 8) << 1) | ((off & 4) << 1) | ((off & 16) >> 2);
#pragma unroll
            for (int nf = 0; nf < 4; ++nf) {
                int col = rowB0 + wc * 64 + nf * 16 + c;       // = h*64 + d
                float bvv = bias[col];
                int hh = col >> 6, d = col & 63;
                ushort4 o;
                o.x = f2bf(acc[mf][nf][0] + bvv);
                o.y = f2bf(acc[mf][nf][1] + bvv);
                o.z = f2bf(acc[mf][nf][2] + bvv);
                o.w = f2bf(acc[mf][nf][3] + bvv);
                size_t addr = (((size_t)(bb * H_ + hh)) * HD_ + d) * T_ + blk * 64 + slot;
                *reinterpret_cast<ushort4*>(&vT[addr]) = o;
            }
        }
    } else {
        unsigned short* out = z == 0 ? oq : ok;
#pragma unroll
        for (int mf = 0; mf < 4; ++mf)
#pragma unroll
            for (int nf = 0; nf < 4; ++nf) {
                int col = rowB0 + wc * 64 + nf * 16 + c;
                float bvv = bias[col];
#pragma unroll
                for (int j = 0; j < 4; ++j) {
                    int row = rowA0 + wr * 64 + mf * 16 + g * 4 + j;
                    float v = (acc[mf][nf][j] + bvv) * oscale;
                    out[(size_t)row * N + col] = f2bf(v);
                }
            }
    }
}

// ---------------- O projection GEMM (fp32 out, single-buffer, XCD swizzle) ----------------
__global__ __launch_bounds__(256, 3)
void gemm_o(const unsigned short* __restrict__ A, const unsigned short* __restrict__ W,
            const float* __restrict__ bias, float* __restrict__ out) {
    constexpr int K = 1024, N = 1024, BK = 64;
    __shared__ unsigned short sA[128 * BK];
    __shared__ unsigned short sB[128 * BK];
    const int tid = threadIdx.x;
    const int lane = tid & 63, w = tid >> 6;
    const int c = lane & 15, g = lane >> 4;
    // XCD swizzle: 512 blocks -> 64 contiguous (bm,bn) per XCD
    const int flat = blockIdx.x + (blockIdx.y << 3);
    const int nbz = (flat & 7) * 64 + (flat >> 3);
    const int bm = nbz >> 3, bn = nbz & 7;
    const int wr = w >> 1, wc = w & 1;
    const int rowA0 = bm * 128, rowB0 = bn * 128;

    f32x4 acc[4][4] = {};

    for (int k0 = 0; k0 < K; k0 += BK) {
        __syncthreads();
#pragma unroll
        for (int i = 0; i < 4; ++i) {
            int chunk = tid + i * 256;
            int row = chunk >> 3, c16 = chunk & 7;
            int sc16 = c16 ^ (row & 7);
            gll16(A + (size_t)(rowA0 + row) * K + k0 + sc16 * 8, (char*)sA + chunk * 16);
            gll16(W + (size_t)(rowB0 + row) * K + k0 + sc16 * 8, (char*)sB + chunk * 16);
        }
        __syncthreads();
#pragma unroll
        for (int kk = 0; kk < 2; ++kk) {
            bf16x8 af[4], bfr[4];
#pragma unroll
            for (int mf = 0; mf < 4; ++mf) {
                int row = wr * 64 + mf * 16 + c;
                int off = (row * 128 + kk * 64 + g * 16) ^ ((row & 7) << 4);
                af[mf] = *reinterpret_cast<const bf16x8*>((const char*)sA + off);
            }
#pragma unroll
            for (int nf = 0; nf < 4; ++nf) {
                int row = wc * 64 + nf * 16 + c;
                int off = (row * 128 + kk * 64 + g * 16) ^ ((row & 7) << 4);
                bfr[nf] = *reinterpret_cast<const bf16x8*>((const char*)sB + off);
            }
#pragma unroll
            for (int mf = 0; mf < 4; ++mf)
#pragma unroll
                for (int nf = 0; nf < 4; ++nf)
                    acc[mf][nf] = __builtin_amdgcn_mfma_f32_16x16x32_bf16(af[mf], bfr[nf], acc[mf][nf], 0, 0, 0);
        }
    }
#pragma unroll
    for (int mf = 0; mf < 4; ++mf)
#pragma unroll
        for (int nf = 0; nf < 4; ++nf) {
            int col = rowB0 + wc * 64 + nf * 16 + c;
            float bvv = bias[col];
#pragma unroll
            for (int j = 0; j < 4; ++j) {
                int row = rowA0 + wr * 64 + mf * 16 + g * 4 + j;
                out[(size_t)row * N + col] = acc[mf][nf][j] + bvv;
            }
        }
}

// ---------------- flash attention: r15 version (256 thr, u=2, static-max, ones-MFMA) ----------------
__global__ __launch_bounds__(256, 4)
void flash_kernel(const unsigned short* __restrict__ qbf,   // [B][T][D], pre-scaled log2e/8
                  const unsigned short* __restrict__ kbf,   // [B][T][D]
                  const unsigned short* __restrict__ vT,    // [B][H][HD][T] s-permuted
                  unsigned short* __restrict__ ohbf,        // [B][T][D]
                  float* __restrict__ madjOut) {            // [B][H][T]: 4 + log2(l)
    __shared__ unsigned short sK[2][64 * 64];    // dbuf, 2x8KB
    __shared__ unsigned short sV[2][64 * 64];    // dbuf, 2x8KB
    const int tid = threadIdx.x, lane = tid & 63, w = tid >> 6;
    const int c = lane & 15, g = lane >> 4;
    const int nb = (blockIdx.x & 7) * 128 + (blockIdx.x >> 3);
    const int t0 = (nb & 15) * 128, h = (nb >> 4) & 15, b = nb >> 8;

    bf16x8 qf[2][2];
#pragma unroll
    for (int u = 0; u < 2; ++u) {
        const size_t qbase = ((size_t)(b * T_) + t0 + w * 32 + u * 16 + c) * D_ + h * HD_;
        qf[u][0] = *reinterpret_cast<const bf16x8*>(qbf + qbase + g * 8);
        qf[u][1] = *reinterpret_cast<const bf16x8*>(qbf + qbase + 32 + g * 8);
    }

    const unsigned short one_bf = 0x3F80;
    const bf16x8 ones = { (short)one_bf, (short)one_bf, (short)one_bf, (short)one_bf,
                          (short)one_bf, (short)one_bf, (short)one_bf, (short)one_bf };

    f32x4 acc[2][4] = {};    // O numerator
    f32x4 acc_l[2] = {};     // l via ones-column; acc_l[u][j] = l for row g*4+j

    const unsigned short* kRow = kbf + (size_t)b * T_ * D_ + h * HD_;
    const unsigned short* vRow = vT + ((size_t)(b * H_ + h)) * HD_ * T_;

    auto stage = [&](int buf, int s0) {
#pragma unroll
        for (int i = 0; i < 2; ++i) {
            int chunk = tid + i * 256;
            int row = chunk >> 3, c16 = chunk & 7;
            int sc16 = c16 ^ (row & 7);
            gll16(kRow + (size_t)(s0 + row) * D_ + sc16 * 8, (char*)sK[buf] + chunk * 16);
            gll16(vRow + (size_t)row * T_ + s0 + sc16 * 8, (char*)sV[buf] + chunk * 16);
        }
    };

    stage(0, 0);   // L_0 in flight
    constexpr int NT = T_ / 64;

    for (int it = 0; it < NT; ++it) {
        const int cur = it & 1;
        if (it + 1 < NT) {
            stage(cur ^ 1, (it + 1) * 64);   // issue L_{it+1} (4 loads)
            asm volatile("s_waitcnt vmcnt(4)" ::: "memory");  // wait L_it only
        } else {
            asm volatile("s_waitcnt vmcnt(0)" ::: "memory");
        }
        RAW_BAR();                           // buf[cur] fully staged for all waves

        const char* sKc = (const char*)sK[cur];
        const char* sVc = (const char*)sV[cur];

        f32x4 sc[2][4] = {};
        __builtin_amdgcn_s_setprio(1);
#pragma unroll
        for (int kk = 0; kk < 2; ++kk)
#pragma unroll
            for (int nf = 0; nf < 4; ++nf) {
                int row = nf * 16 + c;
                int off = (row * 128 + kk * 64 + g * 16) ^ ((row & 7) << 4);
                bf16x8 kf = *reinterpret_cast<const bf16x8*>(sKc + off);
                sc[0][nf] = __builtin_amdgcn_mfma_f32_16x16x32_bf16(kf, qf[0][kk], sc[0][nf], 0, 0, 0);
                sc[1][nf] = __builtin_amdgcn_mfma_f32_16x16x32_bf16(kf, qf[1][kk], sc[1][nf], 0, 0, 0);
            }
        __builtin_amdgcn_s_setprio(0);

        // static-max softmax: p = exp2(s), no branch, no reductions
        u32x4 pkw[2][2];
#pragma unroll
        for (int u = 0; u < 2; ++u) {
#pragma unroll
            for (int nf = 0; nf < 4; ++nf)
#pragma unroll
                for (int j = 0; j < 4; ++j)
                    sc[u][nf][j] = fexp2(sc[u][nf][j]);
#pragma unroll
            for (int kk = 0; kk < 2; ++kk) {
                u32x4 pw;
                pw.x = cvt_pk_bf16(sc[u][2 * kk][0], sc[u][2 * kk][1]);
                pw.y = cvt_pk_bf16(sc[u][2 * kk][2], sc[u][2 * kk][3]);
                pw.z = cvt_pk_bf16(sc[u][2 * kk + 1][0], sc[u][2 * kk + 1][1]);
                pw.w = cvt_pk_bf16(sc[u][2 * kk + 1][2], sc[u][2 * kk + 1][3]);
                pkw[u][kk] = pw;
            }
        }

        __builtin_amdgcn_s_setprio(1);
#pragma unroll
        for (int kk = 0; kk < 2; ++kk) {
            bf16x8 pa0 = __builtin_bit_cast(bf16x8, pkw[0][kk]);
            bf16x8 pa1 = __builtin_bit_cast(bf16x8, pkw[1][kk]);
#pragma unroll
            for (int nf = 0; nf < 4; ++nf) {
                int row = nf * 16 + c;
                int voff = (row * 128 + kk * 64 + g * 16) ^ ((row & 7) << 4);
                bf16x8 vf = *reinterpret_cast<const bf16x8*>(sVc + voff);
                acc[0][nf] = __builtin_amdgcn_mfma_f32_16x16x32_bf16(pa0, vf, acc[0][nf], 0, 0, 0);
                acc[1][nf] = __builtin_amdgcn_mfma_f32_16x16x32_bf16(pa1, vf, acc[1][nf], 0, 0, 0);
            }
            // l accumulation: ones-column MFMA (row sums, lane-local result)
            acc_l[0] = __builtin_amdgcn_mfma_f32_16x16x32_bf16(pa0, ones, acc_l[0], 0, 0, 0);
            acc_l[1] = __builtin_amdgcn_mfma_f32_16x16x32_bf16(pa1, ones, acc_l[1], 0, 0, 0);
        }
        __builtin_amdgcn_s_setprio(0);
        RAW_BAR();   // all waves done reading buf[cur] before it is re-staged
    }

#pragma unroll
    for (int u = 0; u < 2; ++u) {
#pragma unroll
        for (int j = 0; j < 4; ++j) {
            float inv = 1.f / acc_l[u][j];     // lane-local: l for row g*4+j
            int trow = t0 + w * 32 + u * 16 + g * 4 + j;
#pragma unroll
            for (int nf = 0; nf < 4; ++nf)
                ohbf[((size_t)(b * T_) + trow) * D_ + h * HD_ + nf * 16 + c] = f2bf(acc[u][nf][j] * inv);
            if (c == 0)
                madjOut[((size_t)(b * H_ + h)) * T_ + trow] = 4.0f + __log2f(acc_l[u][j]);
        }
    }
}

// ---------------- weight: 512 threads, t128 x s128 tile, madj via LDS ----------------
__global__ __launch_bounds__(512, 4)
void weight_kernel(const unsigned short* __restrict__ qbf,
                   const unsigned short* __restrict__ kbf,
                   const float* __restrict__ madjIn,
                   float* __restrict__ wout) {
    __shared__ unsigned short sQ[2][128 * 64];   // dbuf, 2x16KB
    __shared__ unsigned short sK2[2][128 * 64];  // dbuf, 2x16KB
    __shared__ float sMadj[16][128];             // 8KB
    const int tid = threadIdx.x, lane = tid & 63, w = tid >> 6;  // w in [0,8)
    const int c = lane & 15, g = lane >> 4;
    const int wr = w >> 2, wc = w & 3;   // wave grid: 2 (t) x 4 (s)
    // XCD swizzle: 1024 blocks -> 128 contiguous per XCD
    const int nb = (blockIdx.x & 7) * 128 + (blockIdx.x >> 3);
    const int s0 = (nb & 15) * 128, t0 = ((nb >> 4) & 15) * 128, b = nb >> 8;

    float wacc[4][2][4] = {};

    auto stageW = [&](int buf, int h) {
#pragma unroll
        for (int i = 0; i < 2; ++i) {
            int chunk = tid + i * 512;        // 0..1023 (Q: 128 rows x 64)
            int row = chunk >> 3, c16 = chunk & 7;
            int sc16 = c16 ^ (row & 7);
            gll16(qbf + ((size_t)(b * T_) + t0 + row) * D_ + h * HD_ + sc16 * 8,
                  (char*)sQ[buf] + chunk * 16);
        }
#pragma unroll
        for (int i = 0; i < 2; ++i) {
            int chunk = tid + i * 512;        // 0..1023 (K: 128 rows x 64)
            int row = chunk >> 3, c16 = chunk & 7;
            int sc16 = c16 ^ (row & 7);
            gll16(kbf + ((size_t)(b * T_) + s0 + row) * D_ + h * HD_ + sc16 * 8,
                  (char*)sK2[buf] + chunk * 16);
        }
    };

    // one-time: preload madj[16 heads][128 t-rows] into LDS (coalesced float4/thread)
    {
        int hh = tid >> 5, tq = tid & 31;
        float4 mv = *reinterpret_cast<const float4*>(
            &madjIn[((size_t)(b * H_ + hh)) * T_ + t0 + tq * 4]);
        *reinterpret_cast<float4*>(&sMadj[hh][tq * 4]) = mv;
    }
    __syncthreads();

    stageW(0, 0);   // L_0 in flight (4 loads/thread)

    for (int h = 0; h < H_; ++h) {
        const int cur = h & 1;
        if (h + 1 < H_) {
            stageW(cur ^ 1, h + 1);          // issue L_{h+1} (4 loads)
            asm volatile("s_waitcnt vmcnt(4)" ::: "memory");  // wait L_h only
        } else {
            asm volatile("s_waitcnt vmcnt(0)" ::: "memory");
        }
        RAW_BAR();

        const char* sQc = (const char*)sQ[cur];
        const char* sKc = (const char*)sK2[cur];

        // C-init = -madj[h][local trow] from LDS
        f32x4 sc[4][2];
#pragma unroll
        for (int mf = 0; mf < 4; ++mf) {
            f32x4 mrow = *reinterpret_cast<const f32x4*>(&sMadj[h][wr * 64 + mf * 16 + g * 4]);
#pragma unroll
            for (int j = 0; j < 4; ++j) {
                sc[mf][0][j] = -mrow[j];
                sc[mf][1][j] = -mrow[j];
            }
        }

        __builtin_amdgcn_s_setprio(1);
#pragma unroll
        for (int kk = 0; kk < 2; ++kk) {
            bf16x8 af[4], bfr[2];
#pragma unroll
            for (int mf = 0; mf < 4; ++mf) {
                int row = wr * 64 + mf * 16 + c;
                int off = (row * 128 + kk * 64 + g * 16) ^ ((row & 7) << 4);
                af[mf] = *reinterpret_cast<const bf16x8*>(sQc + off);
            }
#pragma unroll
            for (int nf = 0; nf < 2; ++nf) {
                int row = wc * 32 + nf * 16 + c;
                int off = (row * 128 + kk * 64 + g * 16) ^ ((row & 7) << 4);
                bfr[nf] = *reinterpret_cast<const bf16x8*>(sKc + off);
            }
#pragma unroll
            for (int mf = 0; mf < 4; ++mf)
#pragma unroll
                for (int nf = 0; nf < 2; ++nf)
                    sc[mf][nf] = __builtin_amdgcn_mfma_f32_16x16x32_bf16(af[mf], bfr[nf], sc[mf][nf], 0, 0, 0);
        }
        __builtin_amdgcn_s_setprio(0);
#pragma unroll
        for (int mf = 0; mf < 4; ++mf)
#pragma unroll
            for (int nf = 0; nf < 2; ++nf)
#pragma unroll
                for (int j = 0; j < 4; ++j)
                    wacc[mf][nf][j] += fexp2(sc[mf][nf][j]);
        RAW_BAR();
    }
#pragma unroll
    for (int mf = 0; mf < 4; ++mf)
#pragma unroll
        for (int j = 0; j < 4; ++j) {
            int trow = t0 + wr * 64 + mf * 16 + g * 4 + j;
#pragma unroll
            for (int nf = 0; nf < 2; ++nf) {
                int col = s0 + wc * 32 + nf * 16 + c;
                wout[((size_t)b * T_ + trow) * (size_t)T_ + col] = wacc[mf][nf][j];
            }
        }
}

extern "C" void kernel_launch(void* const* d_in, const int* in_sizes, int n_in,
                              void* d_out, int out_size, void* d_ws, size_t ws_size,
                              hipStream_t stream) {
    const float* Q  = (const float*)d_in[0];
    const float* K  = (const float*)d_in[1];
    const float* V  = (const float*)d_in[2];
    const float* Wq = (const float*)d_in[3];
    const float* bq = (const float*)d_in[4];
    const float* Wk = (const float*)d_in[5];
    const float* bk = (const float*)d_in[6];
    const float* Wv = (const float*)d_in[7];
    const float* bv = (const float*)d_in[8];
    const float* Wo = (const float*)d_in[9];
    const float* bo = (const float*)d_in[10];

    char* ws = (char*)d_ws;
    const size_t MB = 1u << 20;
    unsigned short* Wqb = (unsigned short*)(ws);
    unsigned short* Wkb = Wqb + 1024 * 1024;
    unsigned short* Wvb = Wkb + 1024 * 1024;
    unsigned short* Wob = Wvb + 1024 * 1024;                 // ends @8MB
    unsigned short* Qc  = (unsigned short*)(ws + 8 * MB);    // 16MB
    unsigned short* Kc  = (unsigned short*)(ws + 24 * MB);   // 16MB
    unsigned short* Vc  = (unsigned short*)(ws + 40 * MB);   // 16MB
    unsigned short* qb  = (unsigned short*)(ws + 56 * MB);   // 16MB
    unsigned short* kb  = (unsigned short*)(ws + 72 * MB);   // 16MB
    unsigned short* vT  = (unsigned short*)(ws + 88 * MB);   // 16MB (direct from gemm_qkv)
    unsigned short* ohb = Kc;    // alias: Kc dead after gemm_qkv
    float* mArr = (float*)(ws + 104 * MB);                   // 512KB (madj)

    cast_fused<<<dim3(1024, 7), 256, 0, stream>>>(Q, K, V, Wq, Wk, Wv, Wo,
                                                  Qc, Kc, Vc, Wqb, Wkb, Wvb, Wob);

    gemm_qkv<<<dim3(8, 64, 3), 256, 0, stream>>>(Qc, Kc, Vc, Wqb, Wkb, Wvb,
                                                 bq, bk, bv, qb, kb, vT);

    flash_kernel<<<1024, 256, 0, stream>>>(qb, kb, vT, ohb, mArr);

    float* Oout = (float*)d_out;
    float* Wout = Oout + (size_t)BT_ * D_;
    gemm_o<<<dim3(8, 64), 256, 0, stream>>>(ohb, Wob, bo, Oout);
    weight_kernel<<<1024, 512, 0, stream>>>(qb, kb, mArr, Wout);
}